// Round 3
// baseline (215.571 us; speedup 1.0000x reference)
//
#include <hip/hip_runtime.h>

#define NUM_NODES 100000
#define NUM_EDGES 400000
#define F_IN 16
#define F_EDGE 8
#define EMB 16
#define NUM_GRAPHS 256

#define ET 10                                          // 16-edge tiles per block
#define EDGE_BLOCKS (NUM_EDGES / (16 * ET))            // 2500

// ---------------------------------------------------------------------------
// Workspace (zeroed each launch): sums : NUM_NODES*EMB f32, cnt : NUM_NODES f32
// (gmax/gsum/gcnt removed: pooling+head now fused into graph_kernel, no atomics)
// ---------------------------------------------------------------------------

// v4 edge kernel: ZERO LDS. v3's counters showed the LDS pipe co-limiting:
// 32 ds_read_b128/thread/tile (weights re-read every tile) = ~31 us of LDS
// occupancy vs ~15 us VALU floor. Weights for one o-channel are only 128
// floats -> held in VGPRs, loaded once per block (L2-hot, 8 KB total).
// Occupancy was already 2 waves/SIMD (VGPR 80 + 13.8KB LDS), so spending
// ~215 VGPR costs no occupancy. Keeps v3's proven structure: src-index
// preload + double-buffered tile pipeline + coarse sched_barrier fences.
// Thread (e = tid&15, o = tid>>4) handles edge (tile*16+e), channel o.
__global__ __launch_bounds__(256, 2) void edge_kernel(
    const float* __restrict__ x, const int* __restrict__ ei,
    const float* __restrict__ ea, const float* __restrict__ nn1_w,
    const float* __restrict__ nn1_b, float* __restrict__ sums,
    float* __restrict__ cnt)
{
    const int tid = threadIdx.x;
    const int e   = tid & 15;
    const int o   = tid >> 4;
    const int eb0 = blockIdx.x * (16 * ET);

    // ---- all src indices issued FIRST (latency hides under weight loads)
    int srcT[ET];
    #pragma unroll
    for (int t = 0; t < ET; t++) srcT[t] = ei[eb0 + t * 16 + e];
    __builtin_amdgcn_sched_barrier(0);

    // ---- weights + bias for channel o into registers (once per block)
    //      wr row i: nn1_w[(i*16+o)*8 .. +8]; br[i] = nn1_b[i*16+o]
    float4 w0r[F_IN], w1r[F_IN];
    float  br[F_IN];
    #pragma unroll
    for (int i = 0; i < F_IN; i++) {
        const float* wp = &nn1_w[(i * 16 + o) * 8];
        w0r[i] = *(const float4*)wp;
        w1r[i] = *(const float4*)(wp + 4);
        br[i]  = nn1_b[i * 16 + o];
    }
    __builtin_amdgcn_sched_barrier(0);

    // T is compile-time constant at every expansion (loop fully unrolled)
    // so srcT[T] and the w/br arrays stay in registers.
#define LOAD_TILE(T, A0, A1, XR, D) do {                                    \
        const int eI = eb0 + (T) * 16 + e;                                  \
        D  = ei[NUM_EDGES + eI];                                            \
        A0 = *(const float4*)&ea[eI * 8];                                   \
        A1 = *(const float4*)&ea[eI * 8 + 4];                               \
        _Pragma("unroll")                                                   \
        for (int r = 0; r < 4; r++) {                                       \
            const float4 v = *(const float4*)&x[srcT[T] * 16 + 4 * r];      \
            XR[4*r+0] = v.x; XR[4*r+1] = v.y;                               \
            XR[4*r+2] = v.z; XR[4*r+3] = v.w;                               \
        }                                                                   \
    } while (0)

    // FMA ordering identical to v3 per (edge, o) pair (bit-exact output).
#define COMPUTE_TILE(A0, A1, XR, D) do {                                    \
        float acc = 0.f;                                                    \
        _Pragma("unroll")                                                   \
        for (int i = 0; i < F_IN; i++) {                                    \
            float u = br[i];                                                \
            u = fmaf(A0.x, w0r[i].x, u); u = fmaf(A0.y, w0r[i].y, u);       \
            u = fmaf(A0.z, w0r[i].z, u); u = fmaf(A0.w, w0r[i].w, u);       \
            u = fmaf(A1.x, w1r[i].x, u); u = fmaf(A1.y, w1r[i].y, u);       \
            u = fmaf(A1.z, w1r[i].z, u); u = fmaf(A1.w, w1r[i].w, u);       \
            acc = fmaf(XR[i], fmaxf(u, 0.f), acc);                          \
        }                                                                   \
        atomicAdd(&sums[D * 16 + o], acc);                                  \
        if (o == 0) atomicAdd(&cnt[D], 1.f);                                \
    } while (0)

    float4 pA0, pA1; float pX[F_IN]; int pD;
    float4 qA0, qA1; float qX[F_IN]; int qD;

    LOAD_TILE(0, pA0, pA1, pX, pD);
    #pragma unroll
    for (int t = 0; t < ET; t++) {
        if ((t & 1) == 0) {
            if (t + 1 < ET) LOAD_TILE(t + 1, qA0, qA1, qX, qD);
            __builtin_amdgcn_sched_barrier(0);   // loads(t+1) stay above compute(t)
            COMPUTE_TILE(pA0, pA1, pX, pD);
        } else {
            if (t + 1 < ET) LOAD_TILE(t + 1, pA0, pA1, pX, pD);
            __builtin_amdgcn_sched_barrier(0);
            COMPUTE_TILE(qA0, qA1, qX, qD);
        }
    }
#undef LOAD_TILE
#undef COMPUTE_TILE
}

// One block per GRAPH (batch is sorted). Replaces node_kernel + head_kernel.
// Binary-search the node range [start,end); stream nodes in 16-node tiles:
// thread (j = tid>>4, o = tid&15) computes h[base+j][o]; the x row is
// accessed via intra-wave shuffle (wave = 4 j-values x 16 o-values, so
// x[n][i] lives in lane ((j&3)<<4)|i ) -- no LDS staging, no barriers, no
// serial flusher, and NO pooling atomics: per-thread register accumulators
// -> wave tree-reduce -> cross-wave LDS reduce -> fused head MLP -> out[g].
__global__ __launch_bounds__(256) void graph_kernel(
    const float* __restrict__ x, const int* __restrict__ batch,
    const float* __restrict__ root_w, const float* __restrict__ conv_b,
    const float* __restrict__ sums, const float* __restrict__ cnt,
    const float* __restrict__ lin1_w, const float* __restrict__ lin1_b,
    const float* __restrict__ lin2_w, const float* __restrict__ lin2_b,
    float* __restrict__ out)
{
    __shared__ float redM[4][16];
    __shared__ float redS[4][16];

    const int g   = blockIdx.x;
    const int tid = threadIdx.x;
    const int j   = tid >> 4;
    const int o   = tid & 15;
    const int jw  = j & 3;             // j within the 64-lane wave

    // root_w row o into registers: rwr[i] = root_w[o*16+i]
    float rwr[F_IN];
    #pragma unroll
    for (int r = 0; r < 4; r++) {
        const float4 v = *(const float4*)&root_w[o * 16 + 4 * r];
        rwr[4*r+0] = v.x; rwr[4*r+1] = v.y; rwr[4*r+2] = v.z; rwr[4*r+3] = v.w;
    }
    const float cb = conv_b[o];

    // Interleaved binary searches (batch sorted, block-uniform -> no
    // divergence; the two dependent-load chains overlap each other):
    //   start = lower_bound(batch, g), end = lower_bound(batch, g+1)
    int lo0 = 0, hi0 = NUM_NODES, lo1 = 0, hi1 = NUM_NODES;
    while (lo0 < hi0 || lo1 < hi1) {
        const int m0 = (lo0 + hi0) >> 1;
        const int m1 = (lo1 + hi1) >> 1;
        int b0 = 0, b1 = 0;
        if (lo0 < hi0) b0 = batch[m0];
        if (lo1 < hi1) b1 = batch[m1];
        if (lo0 < hi0) { if (b0 < g)     lo0 = m0 + 1; else hi0 = m0; }
        if (lo1 < hi1) { if (b1 < g + 1) lo1 = m1 + 1; else hi1 = m1; }
    }
    const int start = lo0, end = lo1;

    float am = 0.f, asum = 0.f;        // h >= 0, so 0 is a valid max identity

    // software-pipelined main loop (prefetch next tile's 3 loads)
    int base = start;
    float xv = 0.f, sv = 0.f, cv = 1.f;
    if (base < end) {
        const int n = base + j;
        const bool v = n < end;
        xv = v ? x[n * 16 + o]    : 0.f;
        sv = v ? sums[n * 16 + o] : 0.f;
        cv = v ? cnt[n]           : 1.f;
    }
    while (base < end) {
        const int nbase = base + 16;
        float xv1 = 0.f, sv1 = 0.f, cv1 = 1.f;
        if (nbase < end) {
            const int n1 = nbase + j;
            const bool v1 = n1 < end;
            xv1 = v1 ? x[n1 * 16 + o]    : 0.f;
            sv1 = v1 ? sums[n1 * 16 + o] : 0.f;
            cv1 = v1 ? cnt[n1]           : 1.f;
        }
        __builtin_amdgcn_sched_barrier(0);   // prefetch issues before compute

        // h-FMA order identical to old node_kernel (bit-exact per element)
        float a = cb + sv / fmaxf(cv, 1.f);
        #pragma unroll
        for (int i = 0; i < F_IN; i++)
            a = fmaf(__shfl(xv, (jw << 4) | i, 64), rwr[i], a);
        const bool v = (base + j) < end;
        const float h = v ? fmaxf(a, 0.f) : 0.f;
        am = fmaxf(am, h);
        asum += h;

        xv = xv1; sv = sv1; cv = cv1;
        base = nbase;
    }

    // reduce over j: butterfly within wave (j&3), then across 4 waves via LDS
    am   = fmaxf(am, __shfl_xor(am, 16, 64));
    am   = fmaxf(am, __shfl_xor(am, 32, 64));
    asum = asum + __shfl_xor(asum, 16, 64);
    asum = asum + __shfl_xor(asum, 32, 64);
    const int w = tid >> 6;
    if ((tid & 63) < 16) { redM[w][o] = am; redS[w][o] = asum; }
    __syncthreads();

    if (tid < 64) {                     // wave 0: final reduce + head MLP
        const int k = tid & 15;
        const float amF = fmaxf(fmaxf(redM[0][k], redM[1][k]),
                                fmaxf(redM[2][k], redM[3][k]));
        const float asF = (redS[0][k] + redS[1][k]) + (redS[2][k] + redS[3][k]);
        const float c   = fmaxf((float)(end - start), 1.f);
        const float mnF = asF / c;

        // lane k computes a_k; inner cc order matches old head_kernel
        float a = lin1_b[k];
        #pragma unroll
        for (int cc = 0; cc < 16; cc++)
            a = fmaf(__shfl(amF, cc, 64), lin1_w[k * 32 + cc], a);
        #pragma unroll
        for (int cc = 0; cc < 16; cc++)
            a = fmaf(__shfl(mnF, cc, 64), lin1_w[k * 32 + 16 + cc], a);
        const float ra = fmaxf(a, 0.f);

        // serial k-accumulation (same order as old head_kernel)
        float acc = lin2_b[0];
        #pragma unroll
        for (int k2 = 0; k2 < 16; k2++)
            acc = fmaf(__shfl(ra, k2, 64), lin2_w[k2], acc);
        if (tid == 0) out[g] = acc;
    }
}

extern "C" void kernel_launch(void* const* d_in, const int* in_sizes, int n_in,
                              void* d_out, int out_size, void* d_ws, size_t ws_size,
                              hipStream_t stream) {
    const float* x      = (const float*)d_in[0];
    const int*   ei     = (const int*)d_in[1];
    const float* ea     = (const float*)d_in[2];
    const int*   batch  = (const int*)d_in[3];
    const float* nn1_w  = (const float*)d_in[4];
    const float* nn1_b  = (const float*)d_in[5];
    const float* root_w = (const float*)d_in[6];
    const float* conv_b = (const float*)d_in[7];
    const float* lin1_w = (const float*)d_in[8];
    const float* lin1_b = (const float*)d_in[9];
    const float* lin2_w = (const float*)d_in[10];
    const float* lin2_b = (const float*)d_in[11];
    float* out = (float*)d_out;

    float* sums = (float*)d_ws;
    float* cnt  = sums + (size_t)NUM_NODES * EMB;

    const size_t zero_bytes = sizeof(float) * ((size_t)NUM_NODES * EMB + NUM_NODES);
    hipMemsetAsync(d_ws, 0, zero_bytes, stream);

    edge_kernel<<<EDGE_BLOCKS, 256, 0, stream>>>(x, ei, ea, nn1_w, nn1_b, sums, cnt);
    graph_kernel<<<NUM_GRAPHS, 256, 0, stream>>>(
        x, batch, root_w, conv_b, sums, cnt,
        lin1_w, lin1_b, lin2_w, lin2_b, out);
}

// Round 4
// 177.347 us; speedup vs baseline: 1.2155x; 1.2155x over previous
//
#include <hip/hip_runtime.h>

#define NUM_NODES 100000
#define NUM_EDGES 400000
#define F_IN 16
#define F_EDGE 8
#define EMB 16
#define NUM_GRAPHS 256

#define ET 5                                           // 64-edge tiles per block
#define TILE_E 64
#define EDGE_BLOCKS (NUM_EDGES / (TILE_E * ET))        // 1250

// ---------------------------------------------------------------------------
// Workspace (zeroed each launch): sums : NUM_NODES*EMB f32, cnt : NUM_NODES f32
// ---------------------------------------------------------------------------

// v5 edge kernel. Post-mortem of v4 (107us): transposing the thread layout
// de-coalesced the row atomics (WRITE_SIZE 37.5->62.5 MB: one edge's 16
// channels spread over 4 waves -> 4 partial-line RMWs/row), and the compiler
// refused to hold 144 weight VGPRs (VGPR=120 -> L2 re-reads every tile).
// INVARIANT locked here: o = tid&15 (low lane bits) so the 16 lanes of one
// edge's sums-row atomic are adjacent in one wave instruction.
//
// v5 = v3 skeleton (LDS weights, coalesced atomics, upfront src preload
// behind sched_barrier) + 4 edges/thread (64-edge tiles): the 32
// ds_read_b128/wave-tile now serve 16 edges, halving LDS-pipe cost/edge
// (chip floor 31 -> 15.6 us) to balance the ~14 us VALU floor. Single
// buffered tile state (~150 live VGPR) at 3 waves/SIMD: TLP hides the
// per-tile gather stall instead of a register pipeline the compiler keeps
// collapsing.
__global__ __launch_bounds__(256, 3) void edge_kernel(
    const float* __restrict__ x, const int* __restrict__ ei,
    const float* __restrict__ ea, const float* __restrict__ nn1_w,
    const float* __restrict__ nn1_b, float* __restrict__ sums,
    float* __restrict__ cnt)
{
    __shared__ float wtp[256 * 12];   // row r=(i*16+o): 8 weights + 4 pad
    __shared__ float btp[16 * 20];    // btp[o*20+i]

    const int tid = threadIdx.x;
    const int eL  = tid >> 4;         // 0..15
    const int o   = tid & 15;         // LOW bits: atomic-coalescing invariant
    const int eb0 = blockIdx.x * (TILE_E * ET);

    // ---- all src indices issued FIRST (latency hides under weight staging)
    int srcT[ET][4];
    #pragma unroll
    for (int t = 0; t < ET; t++)
        #pragma unroll
        for (int q = 0; q < 4; q++)
            srcT[t][q] = ei[eb0 + t * TILE_E + q * 16 + eL];
    __builtin_amdgcn_sched_barrier(0);   // pin: src loads issue first

    // ---- stage weights, vectorized (row stride 12 floats: 2-way bank = free)
    {
        const float4 w0 = *(const float4*)&nn1_w[tid * 8];
        const float4 w1 = *(const float4*)&nn1_w[tid * 8 + 4];
        *(float4*)&wtp[tid * 12]     = w0;
        *(float4*)&wtp[tid * 12 + 4] = w1;
    }
    btp[(tid & 15) * 20 + (tid >> 4)] = nn1_b[tid];   // tid = i*16+o
    __syncthreads();                                   // the ONLY barrier

    float br[F_IN];
    #pragma unroll
    for (int r = 0; r < 4; r++) {
        const float4 b4 = *(const float4*)&btp[o * 20 + 4 * r];
        br[4 * r + 0] = b4.x; br[4 * r + 1] = b4.y;
        br[4 * r + 2] = b4.z; br[4 * r + 3] = b4.w;
    }

    #pragma unroll
    for (int t = 0; t < ET; t++) {
        // ---- load tile t (dst, ea, x) — issued together at tile top; first
        //      use is ~30 instructions later; 3 waves/SIMD cover the rest.
        int dst[4];
        float4 a0[4], a1[4];
        float X[4][F_IN];
        #pragma unroll
        for (int q = 0; q < 4; q++) {
            const int eI = eb0 + t * TILE_E + q * 16 + eL;
            dst[q] = ei[NUM_EDGES + eI];
            a0[q]  = *(const float4*)&ea[eI * 8];
            a1[q]  = *(const float4*)&ea[eI * 8 + 4];
            #pragma unroll
            for (int r = 0; r < 4; r++) {
                const float4 v = *(const float4*)&x[srcT[t][q] * 16 + 4 * r];
                X[q][4*r+0] = v.x; X[q][4*r+1] = v.y;
                X[q][4*r+2] = v.z; X[q][4*r+3] = v.w;
            }
        }
        __builtin_amdgcn_sched_barrier(0);   // loads stay above compute

        // ---- compute: one LDS weight read per i serves all 4 edges.
        //      Per-edge FMA chain order identical to v3 (bit-exact).
        float acc[4] = {0.f, 0.f, 0.f, 0.f};
        #pragma unroll
        for (int i = 0; i < F_IN; i++) {
            const float* wr = &wtp[(i * 16 + o) * 12];
            const float4 w0 = *(const float4*)wr;
            const float4 w1 = *(const float4*)(wr + 4);
            #pragma unroll
            for (int q = 0; q < 4; q++) {
                float u = br[i];
                u = fmaf(a0[q].x, w0.x, u); u = fmaf(a0[q].y, w0.y, u);
                u = fmaf(a0[q].z, w0.z, u); u = fmaf(a0[q].w, w0.w, u);
                u = fmaf(a1[q].x, w1.x, u); u = fmaf(a1[q].y, w1.y, u);
                u = fmaf(a1[q].z, w1.z, u); u = fmaf(a1[q].w, w1.w, u);
                acc[q] = fmaf(X[q][i], fmaxf(u, 0.f), acc[q]);
            }
        }

        // ---- coalesced row atomics: lanes (eL&3, o=0..15) of each wave
        //      cover 4 whole 64B rows per instruction.
        #pragma unroll
        for (int q = 0; q < 4; q++)
            atomicAdd(&sums[dst[q] * 16 + o], acc[q]);
        if (o == 0) {
            #pragma unroll
            for (int q = 0; q < 4; q++)
                atomicAdd(&cnt[dst[q]], 1.f);
        }
    }
}

// One block per GRAPH (batch is sorted). Replaces node_kernel + head_kernel.
// Binary-search the node range [start,end); stream nodes in 16-node tiles:
// thread (j = tid>>4, o = tid&15) computes h[base+j][o]; the x row is
// accessed via intra-wave shuffle (wave = 4 j-values x 16 o-values, so
// x[n][i] lives in lane ((j&3)<<4)|i ) -- no LDS staging, no barriers, no
// serial flusher, and NO pooling atomics: per-thread register accumulators
// -> wave tree-reduce -> cross-wave LDS reduce -> fused head MLP -> out[g].
// (Unchanged from R3: passed with absmax 0.0; not visible in top-5 counters.)
__global__ __launch_bounds__(256) void graph_kernel(
    const float* __restrict__ x, const int* __restrict__ batch,
    const float* __restrict__ root_w, const float* __restrict__ conv_b,
    const float* __restrict__ sums, const float* __restrict__ cnt,
    const float* __restrict__ lin1_w, const float* __restrict__ lin1_b,
    const float* __restrict__ lin2_w, const float* __restrict__ lin2_b,
    float* __restrict__ out)
{
    __shared__ float redM[4][16];
    __shared__ float redS[4][16];

    const int g   = blockIdx.x;
    const int tid = threadIdx.x;
    const int j   = tid >> 4;
    const int o   = tid & 15;
    const int jw  = j & 3;             // j within the 64-lane wave

    // root_w row o into registers: rwr[i] = root_w[o*16+i]
    float rwr[F_IN];
    #pragma unroll
    for (int r = 0; r < 4; r++) {
        const float4 v = *(const float4*)&root_w[o * 16 + 4 * r];
        rwr[4*r+0] = v.x; rwr[4*r+1] = v.y; rwr[4*r+2] = v.z; rwr[4*r+3] = v.w;
    }
    const float cb = conv_b[o];

    // Interleaved binary searches (batch sorted, block-uniform -> no
    // divergence; the two dependent-load chains overlap each other):
    //   start = lower_bound(batch, g), end = lower_bound(batch, g+1)
    int lo0 = 0, hi0 = NUM_NODES, lo1 = 0, hi1 = NUM_NODES;
    while (lo0 < hi0 || lo1 < hi1) {
        const int m0 = (lo0 + hi0) >> 1;
        const int m1 = (lo1 + hi1) >> 1;
        int b0 = 0, b1 = 0;
        if (lo0 < hi0) b0 = batch[m0];
        if (lo1 < hi1) b1 = batch[m1];
        if (lo0 < hi0) { if (b0 < g)     lo0 = m0 + 1; else hi0 = m0; }
        if (lo1 < hi1) { if (b1 < g + 1) lo1 = m1 + 1; else hi1 = m1; }
    }
    const int start = lo0, end = lo1;

    float am = 0.f, asum = 0.f;        // h >= 0, so 0 is a valid max identity

    // software-pipelined main loop (prefetch next tile's 3 loads)
    int base = start;
    float xv = 0.f, sv = 0.f, cv = 1.f;
    if (base < end) {
        const int n = base + j;
        const bool v = n < end;
        xv = v ? x[n * 16 + o]    : 0.f;
        sv = v ? sums[n * 16 + o] : 0.f;
        cv = v ? cnt[n]           : 1.f;
    }
    while (base < end) {
        const int nbase = base + 16;
        float xv1 = 0.f, sv1 = 0.f, cv1 = 1.f;
        if (nbase < end) {
            const int n1 = nbase + j;
            const bool v1 = n1 < end;
            xv1 = v1 ? x[n1 * 16 + o]    : 0.f;
            sv1 = v1 ? sums[n1 * 16 + o] : 0.f;
            cv1 = v1 ? cnt[n1]           : 1.f;
        }
        __builtin_amdgcn_sched_barrier(0);   // prefetch issues before compute

        // h-FMA order identical to old node_kernel (bit-exact per element)
        float a = cb + sv / fmaxf(cv, 1.f);
        #pragma unroll
        for (int i = 0; i < F_IN; i++)
            a = fmaf(__shfl(xv, (jw << 4) | i, 64), rwr[i], a);
        const bool v = (base + j) < end;
        const float h = v ? fmaxf(a, 0.f) : 0.f;
        am = fmaxf(am, h);
        asum += h;

        xv = xv1; sv = sv1; cv = cv1;
        base = nbase;
    }

    // reduce over j: butterfly within wave (j&3), then across 4 waves via LDS
    am   = fmaxf(am, __shfl_xor(am, 16, 64));
    am   = fmaxf(am, __shfl_xor(am, 32, 64));
    asum = asum + __shfl_xor(asum, 16, 64);
    asum = asum + __shfl_xor(asum, 32, 64);
    const int w = tid >> 6;
    if ((tid & 63) < 16) { redM[w][o] = am; redS[w][o] = asum; }
    __syncthreads();

    if (tid < 64) {                     // wave 0: final reduce + head MLP
        const int k = tid & 15;
        const float amF = fmaxf(fmaxf(redM[0][k], redM[1][k]),
                                fmaxf(redM[2][k], redM[3][k]));
        const float asF = (redS[0][k] + redS[1][k]) + (redS[2][k] + redS[3][k]);
        const float c   = fmaxf((float)(end - start), 1.f);
        const float mnF = asF / c;

        // lane k computes a_k; inner cc order matches old head_kernel
        float a = lin1_b[k];
        #pragma unroll
        for (int cc = 0; cc < 16; cc++)
            a = fmaf(__shfl(amF, cc, 64), lin1_w[k * 32 + cc], a);
        #pragma unroll
        for (int cc = 0; cc < 16; cc++)
            a = fmaf(__shfl(mnF, cc, 64), lin1_w[k * 32 + 16 + cc], a);
        const float ra = fmaxf(a, 0.f);

        // serial k-accumulation (same order as old head_kernel)
        float acc = lin2_b[0];
        #pragma unroll
        for (int k2 = 0; k2 < 16; k2++)
            acc = fmaf(__shfl(ra, k2, 64), lin2_w[k2], acc);
        if (tid == 0) out[g] = acc;
    }
}

extern "C" void kernel_launch(void* const* d_in, const int* in_sizes, int n_in,
                              void* d_out, int out_size, void* d_ws, size_t ws_size,
                              hipStream_t stream) {
    const float* x      = (const float*)d_in[0];
    const int*   ei     = (const int*)d_in[1];
    const float* ea     = (const float*)d_in[2];
    const int*   batch  = (const int*)d_in[3];
    const float* nn1_w  = (const float*)d_in[4];
    const float* nn1_b  = (const float*)d_in[5];
    const float* root_w = (const float*)d_in[6];
    const float* conv_b = (const float*)d_in[7];
    const float* lin1_w = (const float*)d_in[8];
    const float* lin1_b = (const float*)d_in[9];
    const float* lin2_w = (const float*)d_in[10];
    const float* lin2_b = (const float*)d_in[11];
    float* out = (float*)d_out;

    float* sums = (float*)d_ws;
    float* cnt  = sums + (size_t)NUM_NODES * EMB;

    const size_t zero_bytes = sizeof(float) * ((size_t)NUM_NODES * EMB + NUM_NODES);
    hipMemsetAsync(d_ws, 0, zero_bytes, stream);

    edge_kernel<<<EDGE_BLOCKS, 256, 0, stream>>>(x, ei, ea, nn1_w, nn1_b, sums, cnt);
    graph_kernel<<<NUM_GRAPHS, 256, 0, stream>>>(
        x, batch, root_w, conv_b, sums, cnt,
        lin1_w, lin1_b, lin2_w, lin2_b, out);
}